// Round 1
// baseline (1202.638 us; speedup 1.0000x reference)
//
#include <hip/hip_runtime.h>
#include <cmath>
#include <cfloat>

namespace {

constexpr int kB   = 1024;
constexpr int kL   = 64;
constexpr int kHid = 512;
constexpr int kLow = 20;
constexpr int kLM1 = 63;           // L-1
constexpr int kRowElems = kL * kLow;  // 1280 floats per batch row of h0/c0

__device__ __forceinline__ float sigf(float x) {
  return 1.0f / (1.0f + expf(-x));
}

// ---------------------------------------------------------------------------
// Phase 1: h0 = input_h @ W_reduce + b ; c0 = input_c @ W_reduce + b
// One block per (tensor, batch row): 64 tokens x 512 -> 64 x 20.
// ---------------------------------------------------------------------------
__global__ __launch_bounds__(256, 3)
void reduce_kernel(const float* __restrict__ Xh, const float* __restrict__ Xc,
                   const float* __restrict__ W, const float* __restrict__ bv,
                   float* __restrict__ H0, float* __restrict__ C0) {
  __shared__ float xs[64 * 132];   // 64 rows x 128 k (pitch 132 to break banks)
  __shared__ float wsm[128 * 20];  // W chunk

  const int bid = blockIdx.x;
  const float* __restrict__ X = (bid < kB) ? Xh : Xc;
  float* __restrict__ O       = (bid < kB) ? H0 : C0;
  const int b = bid & (kB - 1);
  X += (size_t)b * kL * kHid;
  O += (size_t)b * kRowElems;

  const int tid  = threadIdx.x;
  const int wave = tid >> 6;
  const int lane = tid & 63;

  float acc[20];
#pragma unroll
  for (int d = 0; d < 20; ++d) acc[d] = 0.0f;

  for (int ch = 0; ch < 4; ++ch) {
    __syncthreads();
    // stage X chunk: 64 rows x 128 floats, coalesced float4
#pragma unroll
    for (int r = 0; r < 8; ++r) {
      int f   = r * 256 + tid;          // float4 index within chunk
      int row = f >> 5;
      int c4  = (f & 31) << 2;
      float4 v = *(const float4*)(X + row * kHid + ch * 128 + c4);
      *(float4*)(xs + row * 132 + c4) = v;
    }
    // stage W chunk: 128 x 20
#pragma unroll
    for (int r = 0; r < 10; ++r) {
      int f = r * 256 + tid;
      wsm[f] = W[ch * 2560 + f];
    }
    __syncthreads();
    // compute: lane = token, wave covers k in [wave*32, wave*32+32)
#pragma unroll
    for (int kk = 0; kk < 32; ++kk) {
      int k = wave * 32 + kk;
      float x = xs[lane * 132 + k];
      const float4* wp = (const float4*)(wsm + k * 20);
      float4 w0 = wp[0], w1 = wp[1], w2 = wp[2], w3 = wp[3], w4 = wp[4];
      acc[0]  = fmaf(x, w0.x, acc[0]);  acc[1]  = fmaf(x, w0.y, acc[1]);
      acc[2]  = fmaf(x, w0.z, acc[2]);  acc[3]  = fmaf(x, w0.w, acc[3]);
      acc[4]  = fmaf(x, w1.x, acc[4]);  acc[5]  = fmaf(x, w1.y, acc[5]);
      acc[6]  = fmaf(x, w1.z, acc[6]);  acc[7]  = fmaf(x, w1.w, acc[7]);
      acc[8]  = fmaf(x, w2.x, acc[8]);  acc[9]  = fmaf(x, w2.y, acc[9]);
      acc[10] = fmaf(x, w2.z, acc[10]); acc[11] = fmaf(x, w2.w, acc[11]);
      acc[12] = fmaf(x, w3.x, acc[12]); acc[13] = fmaf(x, w3.y, acc[13]);
      acc[14] = fmaf(x, w3.z, acc[14]); acc[15] = fmaf(x, w3.w, acc[15]);
      acc[16] = fmaf(x, w4.x, acc[16]); acc[17] = fmaf(x, w4.y, acc[17]);
      acc[18] = fmaf(x, w4.z, acc[18]); acc[19] = fmaf(x, w4.w, acc[19]);
    }
  }

  // cross-wave reduction (reuse xs as scratch: needs 4*64*20 = 5120 floats)
  __syncthreads();
  float* red = xs;
#pragma unroll
  for (int d = 0; d < 20; ++d) red[wave * 1280 + lane * 20 + d] = acc[d];
  __syncthreads();
#pragma unroll
  for (int r = 0; r < 5; ++r) {
    int f = r * 256 + tid;  // 1280 outputs, f = t*20 + d
    float s = (red[f] + red[1280 + f]) + (red[2560 + f] + red[3840 + f]);
    O[f] = s + bv[f % 20];
  }
}

// ---------------------------------------------------------------------------
// Phase 2: per-row Gumbel tree pyramid with incremental pair caching.
// One block (256 threads) per batch row. ~39 KB LDS -> 4 blocks/CU.
// ---------------------------------------------------------------------------
__global__ __launch_bounds__(256, 4)
void pyramid_kernel(const float* __restrict__ H0, const float* __restrict__ C0,
                    const float* __restrict__ Wc, const float* __restrict__ bcg,
                    const float* __restrict__ query, const float* __restrict__ U,
                    const int* __restrict__ length, float* __restrict__ out) {
  __shared__ float h_state[64 * 20];
  __shared__ float c_state[64 * 20];
  __shared__ float nh[63 * 20];     // cached pair h_new, indexed by pair SLOT
  __shared__ float nc[63 * 20];     // cached pair c_new
  __shared__ float Wt[100 * 44];    // transposed W_comp: Wt[c][k], pitch 44
  __shared__ float bc[100];
  __shared__ float qv[20];
  __shared__ float lgt[63];         // cached logits, by pair slot
  __shared__ int   idxs[64];        // logical position -> h/c slot
  __shared__ int   pidx[63];        // logical pair -> nh/nc/lgt slot

  const int b    = blockIdx.x;
  const int tid  = threadIdx.x;
  const int wave = tid >> 6;
  const int lane = tid & 63;
  int len = length[b];
  len = len < 1 ? 1 : (len > 64 ? 64 : len);

  // ---- stage ----
  for (int f = tid; f < kRowElems; f += 256) {
    h_state[f] = H0[b * kRowElems + f];
    c_state[f] = C0[b * kRowElems + f];
  }
  for (int f = tid; f < 4000; f += 256) {
    int c = f / 40, k = f - c * 40;
    Wt[c * 44 + k] = Wc[k * 100 + c];
  }
  if (tid < 100) bc[tid] = bcg[tid];
  if (tid < 20)  qv[tid] = query[tid];
  if (tid < 64)  idxs[tid] = tid;
  if (tid < 63)  pidx[tid] = tid;

  // gumbel-noise prefetch: wave w holds row w (valid lanes 0..62)
  const int lclamp = lane < 62 ? lane : 62;
  float u_reg = U[wave * (kB * kLM1) + b * kLM1 + lclamp];

  // fused TreeLSTM eval for one (pair, dim) unit; writes caches, returns h_new
  auto eval_unit = [&](int a, int b2, int ps, int dd) -> float {
    float ai = bc[dd], af = bc[20 + dd], ag = bc[40 + dd],
          au = bc[60 + dd], ao = bc[80 + dd];
#pragma unroll
    for (int kq = 0; kq < 10; ++kq) {
      const float4 xq = (kq < 5)
          ? *(const float4*)(h_state + a * 20 + kq * 4)
          : *(const float4*)(h_state + b2 * 20 + (kq - 5) * 4);
      const float4 wi = *(const float4*)(Wt + (dd)      * 44 + kq * 4);
      const float4 wf = *(const float4*)(Wt + (20 + dd) * 44 + kq * 4);
      const float4 wg = *(const float4*)(Wt + (40 + dd) * 44 + kq * 4);
      const float4 wu = *(const float4*)(Wt + (60 + dd) * 44 + kq * 4);
      const float4 wo = *(const float4*)(Wt + (80 + dd) * 44 + kq * 4);
      ai = fmaf(xq.x, wi.x, ai); ai = fmaf(xq.y, wi.y, ai);
      ai = fmaf(xq.z, wi.z, ai); ai = fmaf(xq.w, wi.w, ai);
      af = fmaf(xq.x, wf.x, af); af = fmaf(xq.y, wf.y, af);
      af = fmaf(xq.z, wf.z, af); af = fmaf(xq.w, wf.w, af);
      ag = fmaf(xq.x, wg.x, ag); ag = fmaf(xq.y, wg.y, ag);
      ag = fmaf(xq.z, wg.z, ag); ag = fmaf(xq.w, wg.w, ag);
      au = fmaf(xq.x, wu.x, au); au = fmaf(xq.y, wu.y, au);
      au = fmaf(xq.z, wu.z, au); au = fmaf(xq.w, wu.w, au);
      ao = fmaf(xq.x, wo.x, ao); ao = fmaf(xq.y, wo.y, ao);
      ao = fmaf(xq.z, wo.z, ao); ao = fmaf(xq.w, wo.w, ao);
    }
    float cl = c_state[a * 20 + dd], cr = c_state[b2 * 20 + dd];
    float cn = cl * sigf(af + 1.0f) + cr * sigf(ag + 1.0f) + tanhf(au) * sigf(ai);
    float hn = sigf(ao) * tanhf(cn);
    nh[ps * 20 + dd] = hn;
    nc[ps * 20 + dd] = cn;
    return hn;
  };

  __syncthreads();

  // ---- init: evaluate all 63 pairs ----
#pragma unroll
  for (int r = 0; r < 5; ++r) {
    int u = r * 256 + tid;
    if (u < 1260) {
      int p = u / 20, dd = u - p * 20;
      (void)eval_unit(p, p + 1, p, dd);
    }
  }
  __syncthreads();
  if (tid < 63) {
    float s = 0.0f;
#pragma unroll
    for (int d = 0; d < 20; ++d) s = fmaf(nh[tid * 20 + d], qv[d], s);
    lgt[tid] = s;
  }

  const int nIter = len - 1;
  for (int i = 0; i < nIter; ++i) {
    __syncthreads();
    if (wave == (i & 3)) {
      const int n = kL - i;  // current sequence length

      // ---- z = logit + gumbel; argmax (ties -> lowest index) ----
      int   j  = lane;
      float zz = -FLT_MAX;
      bool valid = (j <= n - 2) && ((i + 1 + j) < len);
      if (valid) {
        float g = -logf(-logf(u_reg + 1e-20f) + 1e-20f);
        zz = lgt[pidx[j]] + g;
      }
      int ji = j;
#pragma unroll
      for (int off = 32; off > 0; off >>= 1) {
        float oz = __shfl_xor(zz, off);
        int   oi = __shfl_xor(ji, off);
        if (oz > zz || (oz == zz && oi < ji)) { zz = oz; ji = oi; }
      }
      const int k = ji;  // wave-uniform

      // ---- merge: write merged value, shift index arrays ----
      const int tgt = idxs[k];
      const int psk = pidx[k];
      float nhv = 0.0f, ncv = 0.0f;
      if (lane < 20) { nhv = nh[psk * 20 + lane]; ncv = nc[psk * 20 + lane]; }
      bool doI = (lane >= k + 1) && (lane <= n - 2);
      bool doP = (lane >= k + 1) && (lane <= n - 3);
      int vI = doI ? idxs[lane + 1] : 0;
      int vP = doP ? pidx[lane + 1] : 0;
      __builtin_amdgcn_wave_barrier();  // keep reads scheduled before writes
      if (lane < 20) {
        h_state[tgt * 20 + lane] = nhv;
        c_state[tgt * 20 + lane] = ncv;
      }
      if (doI) idxs[lane] = vI;
      if (doP) pidx[lane] = vP;

      // ---- evaluate the (<=2) new pairs ----
      if (i < len - 2) {
        int e0 = (k >= 1) ? (k - 1) : k;
        int e1 = k;
        int m  = ((k >= 1) && (k <= n - 3)) ? 2 : 1;
        int p  = lane >> 5, dd = lane & 31;
        bool act = (dd < 20) && (p < m);
        float part = 0.0f;
        int ps = 0;
        if (act) {
          int jj = (p == 0) ? e0 : e1;
          int a  = idxs[jj], b2 = idxs[jj + 1];
          ps = pidx[jj];
          float hn = eval_unit(a, b2, ps, dd);
          part = hn * qv[dd];
        }
#pragma unroll
        for (int off = 16; off > 0; off >>= 1) part += __shfl_xor(part, off);
        if (act && dd == 0) lgt[ps] = part;
      }

      // ---- prefetch gumbel row for iteration i+4 (this wave's next turn) ----
      if (i + 4 <= 62) {
        u_reg = U[(i + 4) * (kB * kLM1) + b * kLM1 + lclamp];
      }
    }
  }

  __syncthreads();
  if (tid < 20) {
    out[b * 20 + tid] = h_state[idxs[0] * 20 + tid];
  }
}

}  // namespace

extern "C" void kernel_launch(void* const* d_in, const int* in_sizes, int n_in,
                              void* d_out, int out_size, void* d_ws, size_t ws_size,
                              hipStream_t stream) {
  const float* input_h  = (const float*)d_in[0];
  const float* input_c  = (const float*)d_in[1];
  const float* W_reduce = (const float*)d_in[2];
  const float* b_reduce = (const float*)d_in[3];
  const float* W_comp   = (const float*)d_in[4];
  const float* b_comp   = (const float*)d_in[5];
  const float* query    = (const float*)d_in[6];
  const float* u_noise  = (const float*)d_in[7];
  const int*   length   = (const int*)d_in[8];
  float* out = (float*)d_out;

  float* H0 = (float*)d_ws;
  float* C0 = H0 + (size_t)kB * kL * kLow;

  reduce_kernel<<<dim3(2 * kB), dim3(256), 0, stream>>>(
      input_h, input_c, W_reduce, b_reduce, H0, C0);
  pyramid_kernel<<<dim3(kB), dim3(256), 0, stream>>>(
      H0, C0, W_comp, b_comp, query, u_noise, length, out);
}

// Round 2
// 1076.060 us; speedup vs baseline: 1.1176x; 1.1176x over previous
//
#include <hip/hip_runtime.h>
#include <cmath>
#include <cfloat>

namespace {

constexpr int kB   = 1024;
constexpr int kL   = 64;
constexpr int kHid = 512;
constexpr int kLow = 20;
constexpr int kLM1 = 63;              // L-1
constexpr int kRowElems = kL * kLow;  // 1280 floats per batch row of h0/c0

__device__ __forceinline__ float sigf(float x) {
  return 1.0f / (1.0f + expf(-x));
}

// ---------------------------------------------------------------------------
// Phase 1: h0 = input_h @ W_reduce + b ; c0 = input_c @ W_reduce + b
// One block per (tensor, batch row): 64 tokens x 512 -> 64 x 20.
// ---------------------------------------------------------------------------
__global__ __launch_bounds__(256, 3)
void reduce_kernel(const float* __restrict__ Xh, const float* __restrict__ Xc,
                   const float* __restrict__ W, const float* __restrict__ bv,
                   float* __restrict__ H0, float* __restrict__ C0) {
  __shared__ float xs[64 * 132];   // 64 rows x 128 k (pitch 132 to break banks)
  __shared__ float wsm[128 * 20];  // W chunk

  const int bid = blockIdx.x;
  const float* __restrict__ X = (bid < kB) ? Xh : Xc;
  float* __restrict__ O       = (bid < kB) ? H0 : C0;
  const int b = bid & (kB - 1);
  X += (size_t)b * kL * kHid;
  O += (size_t)b * kRowElems;

  const int tid  = threadIdx.x;
  const int wave = tid >> 6;
  const int lane = tid & 63;

  float acc[20];
#pragma unroll
  for (int d = 0; d < 20; ++d) acc[d] = 0.0f;

  for (int ch = 0; ch < 4; ++ch) {
    __syncthreads();
#pragma unroll
    for (int r = 0; r < 8; ++r) {
      int f   = r * 256 + tid;          // float4 index within chunk
      int row = f >> 5;
      int c4  = (f & 31) << 2;
      float4 v = *(const float4*)(X + row * kHid + ch * 128 + c4);
      *(float4*)(xs + row * 132 + c4) = v;
    }
#pragma unroll
    for (int r = 0; r < 10; ++r) {
      int f = r * 256 + tid;
      wsm[f] = W[ch * 2560 + f];
    }
    __syncthreads();
#pragma unroll
    for (int kk = 0; kk < 32; ++kk) {
      int k = wave * 32 + kk;
      float x = xs[lane * 132 + k];
      const float4* wp = (const float4*)(wsm + k * 20);
      float4 w0 = wp[0], w1 = wp[1], w2 = wp[2], w3 = wp[3], w4 = wp[4];
      acc[0]  = fmaf(x, w0.x, acc[0]);  acc[1]  = fmaf(x, w0.y, acc[1]);
      acc[2]  = fmaf(x, w0.z, acc[2]);  acc[3]  = fmaf(x, w0.w, acc[3]);
      acc[4]  = fmaf(x, w1.x, acc[4]);  acc[5]  = fmaf(x, w1.y, acc[5]);
      acc[6]  = fmaf(x, w1.z, acc[6]);  acc[7]  = fmaf(x, w1.w, acc[7]);
      acc[8]  = fmaf(x, w2.x, acc[8]);  acc[9]  = fmaf(x, w2.y, acc[9]);
      acc[10] = fmaf(x, w2.z, acc[10]); acc[11] = fmaf(x, w2.w, acc[11]);
      acc[12] = fmaf(x, w3.x, acc[12]); acc[13] = fmaf(x, w3.y, acc[13]);
      acc[14] = fmaf(x, w3.z, acc[14]); acc[15] = fmaf(x, w3.w, acc[15]);
      acc[16] = fmaf(x, w4.x, acc[16]); acc[17] = fmaf(x, w4.y, acc[17]);
      acc[18] = fmaf(x, w4.z, acc[18]); acc[19] = fmaf(x, w4.w, acc[19]);
    }
  }

  __syncthreads();
  float* red = xs;  // reuse as scratch: 4*64*20 = 5120 floats
#pragma unroll
  for (int d = 0; d < 20; ++d) red[wave * 1280 + lane * 20 + d] = acc[d];
  __syncthreads();
#pragma unroll
  for (int r = 0; r < 5; ++r) {
    int f = r * 256 + tid;  // 1280 outputs, f = t*20 + d
    float s = (red[f] + red[1280 + f]) + (red[2560 + f] + red[3840 + f]);
    O[f] = s + bv[f % 20];
  }
}

// TreeLSTM eval of one (pair, dim) unit, fully inline (macro: keeps __shared__
// address-space inference intact — no lambda, no function-call pointer decay).
// Reads h_state rows A_/B2_, writes nh/nc[PS_*20+DD_], leaves h in HN_.
#define EVAL_UNIT(A_, B2_, PS_, DD_, HN_)                                     \
  {                                                                           \
    float ai = bc[DD_], af = bc[20 + DD_], ag = bc[40 + DD_],                 \
          au = bc[60 + DD_], ao = bc[80 + DD_];                               \
    const int xa_ = (A_)*20, xb_ = (B2_)*20, wr_ = (DD_)*44;                  \
    _Pragma("unroll")                                                         \
    for (int kq = 0; kq < 10; ++kq) {                                         \
      const float4 xq = (kq < 5)                                              \
          ? *(const float4*)(h_state + xa_ + kq * 4)                          \
          : *(const float4*)(h_state + xb_ + (kq - 5) * 4);                   \
      const float4 wi = *(const float4*)(Wt + wr_ + kq * 4);                  \
      const float4 wf = *(const float4*)(Wt + 880  + wr_ + kq * 4);           \
      const float4 wg = *(const float4*)(Wt + 1760 + wr_ + kq * 4);           \
      const float4 wu = *(const float4*)(Wt + 2640 + wr_ + kq * 4);           \
      const float4 wo = *(const float4*)(Wt + 3520 + wr_ + kq * 4);           \
      ai = fmaf(xq.x, wi.x, ai); ai = fmaf(xq.y, wi.y, ai);                   \
      ai = fmaf(xq.z, wi.z, ai); ai = fmaf(xq.w, wi.w, ai);                   \
      af = fmaf(xq.x, wf.x, af); af = fmaf(xq.y, wf.y, af);                   \
      af = fmaf(xq.z, wf.z, af); af = fmaf(xq.w, wf.w, af);                   \
      ag = fmaf(xq.x, wg.x, ag); ag = fmaf(xq.y, wg.y, ag);                   \
      ag = fmaf(xq.z, wg.z, ag); ag = fmaf(xq.w, wg.w, ag);                   \
      au = fmaf(xq.x, wu.x, au); au = fmaf(xq.y, wu.y, au);                   \
      au = fmaf(xq.z, wu.z, au); au = fmaf(xq.w, wu.w, au);                   \
      ao = fmaf(xq.x, wo.x, ao); ao = fmaf(xq.y, wo.y, ao);                   \
      ao = fmaf(xq.z, wo.z, ao); ao = fmaf(xq.w, wo.w, ao);                   \
    }                                                                         \
    const float cl_ = c_state[(A_)*20 + (DD_)],                               \
                cr_ = c_state[(B2_)*20 + (DD_)];                              \
    const float cn_ = cl_ * sigf(af + 1.0f) + cr_ * sigf(ag + 1.0f) +         \
                      tanhf(au) * sigf(ai);                                   \
    (HN_) = sigf(ao) * tanhf(cn_);                                            \
    nh[(PS_)*20 + (DD_)] = (HN_);                                             \
    nc[(PS_)*20 + (DD_)] = cn_;                                               \
  }

// ---------------------------------------------------------------------------
// Phase 2: per-row Gumbel tree pyramid with incremental pair caching.
// One block (256 threads) per batch row. LDS ~39.2 KB -> 4 blocks/CU.
// NO global memory accesses inside the iteration loop (u_noise lives in a
// per-wave register shift-register, Gumbel-transformed at load time).
// ---------------------------------------------------------------------------
__global__ __launch_bounds__(256, 4)
void pyramid_kernel(const float* __restrict__ H0, const float* __restrict__ C0,
                    const float* __restrict__ Wc, const float* __restrict__ bcg,
                    const float* __restrict__ query, const float* __restrict__ U,
                    const int* __restrict__ length, float* __restrict__ out) {
  __shared__ float h_state[64 * 20];
  __shared__ float c_state[64 * 20];
  __shared__ float nh[63 * 20];     // cached pair h_new, indexed by pair SLOT
  __shared__ float nc[63 * 20];     // cached pair c_new
  __shared__ float Wt[100 * 44];    // transposed W_comp: Wt[c][k], pitch 44
  __shared__ float bc[100];
  __shared__ float qv[20];
  __shared__ float lgt[64];         // cached logits, POSITION-indexed (shifted)
  __shared__ int   idxs[64];        // logical position -> h/c slot
  __shared__ int   pidx[64];        // logical pair -> nh/nc slot

  const int b    = blockIdx.x;
  const int tid  = threadIdx.x;
  const int wave = tid >> 6;
  const int lane = tid & 63;
  int len = length[b];
  len = len < 1 ? 1 : (len > 64 ? 64 : len);

  // ---- stage ----
  for (int f = tid; f < kRowElems; f += 256) {
    h_state[f] = H0[b * kRowElems + f];
    c_state[f] = C0[b * kRowElems + f];
  }
  for (int f = tid; f < 4000; f += 256) {
    int c = f / 40, k = f - c * 40;
    Wt[c * 44 + k] = Wc[k * 100 + c];
  }
  if (tid < 100) bc[tid] = bcg[tid];
  if (tid < 20)  qv[tid] = query[tid];
  if (tid < 64)  idxs[tid] = tid;
  if (tid < 64)  pidx[tid] = tid;

  // ---- preload ALL gumbel noise this wave will ever need into registers ----
  // wave w handles iterations i with (i&3)==w, i.e. rows w, w+4, ..., <=62.
  // us[0] is always the current turn's row; shift after each turn.
  const int col = lane < 62 ? lane : 62;  // row has 63 entries; lane 63 unused
  float us[16];
#pragma unroll
  for (int t = 0; t < 16; ++t) {
    us[t] = 0.0f;
    const int row = wave + 4 * t;
    if (row <= 62) {
      const float u = U[row * (kB * kLM1) + b * kLM1 + col];
      us[t] = -logf(-logf(u + 1e-20f) + 1e-20f);  // gumbel, precomputed
    }
  }

  __syncthreads();

  // ---- init: evaluate all 63 adjacent pairs ----
#pragma unroll
  for (int r = 0; r < 5; ++r) {
    int uu = r * 256 + tid;
    if (uu < 1260) {
      int p = uu / 20, dd = uu - p * 20;
      float hn_;
      EVAL_UNIT(p, p + 1, p, dd, hn_);
      (void)hn_;
    }
  }
  __syncthreads();
  if (tid < 63) {
    float s = 0.0f;
#pragma unroll
    for (int d = 0; d < 20; ++d) s = fmaf(nh[tid * 20 + d], qv[d], s);
    lgt[tid] = s;
  }

  const int nIter = len - 1;
  for (int i = 0; i < nIter; ++i) {
    __syncthreads();
    if (wave == (i & 3)) {
      const int n = kL - i;  // current sequence length

      // ---- z = logit + gumbel; argmax (ties -> lowest index) ----
      float zz = -FLT_MAX;
      int   ji = lane;
      const bool valid = (lane <= n - 2) && ((i + 1 + lane) < len);
      if (valid) zz = lgt[lane] + us[0];
#pragma unroll
      for (int off = 32; off > 0; off >>= 1) {
        float oz = __shfl_xor(zz, off);
        int   oi = __shfl_xor(ji, off);
        if (oz > zz || (oz == zz && oi < ji)) { zz = oz; ji = oi; }
      }
      const int k = ji;  // wave-uniform

      // ---- merge: write merged value into slot idxs[k], shift pos arrays ----
      const int tgt = idxs[k];
      const int psk = pidx[k];
      float nhv = 0.0f, ncv = 0.0f;
      if (lane < 20) { nhv = nh[psk * 20 + lane]; ncv = nc[psk * 20 + lane]; }
      const bool doI = (lane >= k + 1) && (lane <= n - 2);
      const bool doP = (lane >= k + 1) && (lane <= n - 3);
      int   vI = doI ? idxs[lane + 1] : 0;
      int   vP = doP ? pidx[lane + 1] : 0;
      float vL = doP ? lgt[lane + 1]  : 0.0f;
      __builtin_amdgcn_wave_barrier();  // keep reads scheduled before writes
      if (lane < 20) {
        h_state[tgt * 20 + lane] = nhv;
        c_state[tgt * 20 + lane] = ncv;
      }
      if (doI) idxs[lane] = vI;
      if (doP) { pidx[lane] = vP; lgt[lane] = vL; }

      // ---- evaluate the (<=2) invalidated pairs, refresh lgt ----
      if (i < len - 2) {
        const int e0 = (k >= 1) ? (k - 1) : k;
        const int m  = ((k >= 1) && (k <= n - 3)) ? 2 : 1;
        const int p  = lane >> 5, dd = lane & 31;
        const bool act = (dd < 20) && (p < m);
        float part = 0.0f;
        int jj = 0;
        if (act) {
          jj = (p == 0) ? e0 : k;
          const int a  = idxs[jj];
          const int b2 = idxs[jj + 1];
          const int ps = pidx[jj];
          float hn_;
          EVAL_UNIT(a, b2, ps, dd, hn_);
          part = hn_ * qv[dd];
        }
#pragma unroll
        for (int off = 16; off > 0; off >>= 1) part += __shfl_xor(part, off);
        if (act && dd == 0) lgt[jj] = part;
      }

      // ---- advance this wave's gumbel shift-register ----
#pragma unroll
      for (int s = 0; s < 15; ++s) us[s] = us[s + 1];
    }
  }

  __syncthreads();
  if (tid < 20) {
    out[b * 20 + tid] = h_state[idxs[0] * 20 + tid];
  }
}

}  // namespace

extern "C" void kernel_launch(void* const* d_in, const int* in_sizes, int n_in,
                              void* d_out, int out_size, void* d_ws, size_t ws_size,
                              hipStream_t stream) {
  const float* input_h  = (const float*)d_in[0];
  const float* input_c  = (const float*)d_in[1];
  const float* W_reduce = (const float*)d_in[2];
  const float* b_reduce = (const float*)d_in[3];
  const float* W_comp   = (const float*)d_in[4];
  const float* b_comp   = (const float*)d_in[5];
  const float* query    = (const float*)d_in[6];
  const float* u_noise  = (const float*)d_in[7];
  const int*   length   = (const int*)d_in[8];
  float* out = (float*)d_out;

  float* H0 = (float*)d_ws;
  float* C0 = H0 + (size_t)kB * kL * kLow;

  reduce_kernel<<<dim3(2 * kB), dim3(256), 0, stream>>>(
      input_h, input_c, W_reduce, b_reduce, H0, C0);
  pyramid_kernel<<<dim3(kB), dim3(256), 0, stream>>>(
      H0, C0, W_comp, b_comp, query, u_noise, length, out);
}

// Round 3
// 241.768 us; speedup vs baseline: 4.9743x; 4.4508x over previous
//
#include <hip/hip_runtime.h>
#include <cmath>
#include <cfloat>

namespace {

constexpr int kB   = 1024;
constexpr int kL   = 64;
constexpr int kHid = 512;
constexpr int kLow = 20;
constexpr int kLM1 = 63;              // L-1
constexpr int kRowElems = kL * kLow;  // 1280 floats per batch row of h0/c0

__device__ __forceinline__ float sigf(float x) {
  return 1.0f / (1.0f + expf(-x));
}

// ---------------------------------------------------------------------------
// Phase 1: h0 = input_h @ W_reduce + b ; c0 = input_c @ W_reduce + b
// One block per (tensor, batch row): 64 tokens x 512 -> 64 x 20.
// (near HBM roofline already; unchanged from R2)
// ---------------------------------------------------------------------------
__global__ __launch_bounds__(256, 3)
void reduce_kernel(const float* __restrict__ Xh, const float* __restrict__ Xc,
                   const float* __restrict__ W, const float* __restrict__ bv,
                   float* __restrict__ H0, float* __restrict__ C0) {
  __shared__ float xs[64 * 132];   // 64 rows x 128 k (pitch 132 to break banks)
  __shared__ float wsm[128 * 20];  // W chunk

  const int bid = blockIdx.x;
  const float* __restrict__ X = (bid < kB) ? Xh : Xc;
  float* __restrict__ O       = (bid < kB) ? H0 : C0;
  const int b = bid & (kB - 1);
  X += (size_t)b * kL * kHid;
  O += (size_t)b * kRowElems;

  const int tid  = threadIdx.x;
  const int wave = tid >> 6;
  const int lane = tid & 63;

  float acc[20];
#pragma unroll
  for (int d = 0; d < 20; ++d) acc[d] = 0.0f;

  for (int ch = 0; ch < 4; ++ch) {
    __syncthreads();
#pragma unroll
    for (int r = 0; r < 8; ++r) {
      int f   = r * 256 + tid;          // float4 index within chunk
      int row = f >> 5;
      int c4  = (f & 31) << 2;
      float4 v = *(const float4*)(X + row * kHid + ch * 128 + c4);
      *(float4*)(xs + row * 132 + c4) = v;
    }
#pragma unroll
    for (int r = 0; r < 10; ++r) {
      int f = r * 256 + tid;
      wsm[f] = W[ch * 2560 + f];
    }
    __syncthreads();
#pragma unroll
    for (int kk = 0; kk < 32; ++kk) {
      int k = wave * 32 + kk;
      float x = xs[lane * 132 + k];
      const float4* wp = (const float4*)(wsm + k * 20);
      float4 w0 = wp[0], w1 = wp[1], w2 = wp[2], w3 = wp[3], w4 = wp[4];
      acc[0]  = fmaf(x, w0.x, acc[0]);  acc[1]  = fmaf(x, w0.y, acc[1]);
      acc[2]  = fmaf(x, w0.z, acc[2]);  acc[3]  = fmaf(x, w0.w, acc[3]);
      acc[4]  = fmaf(x, w1.x, acc[4]);  acc[5]  = fmaf(x, w1.y, acc[5]);
      acc[6]  = fmaf(x, w1.z, acc[6]);  acc[7]  = fmaf(x, w1.w, acc[7]);
      acc[8]  = fmaf(x, w2.x, acc[8]);  acc[9]  = fmaf(x, w2.y, acc[9]);
      acc[10] = fmaf(x, w2.z, acc[10]); acc[11] = fmaf(x, w2.w, acc[11]);
      acc[12] = fmaf(x, w3.x, acc[12]); acc[13] = fmaf(x, w3.y, acc[13]);
      acc[14] = fmaf(x, w3.z, acc[14]); acc[15] = fmaf(x, w3.w, acc[15]);
      acc[16] = fmaf(x, w4.x, acc[16]); acc[17] = fmaf(x, w4.y, acc[17]);
      acc[18] = fmaf(x, w4.z, acc[18]); acc[19] = fmaf(x, w4.w, acc[19]);
    }
  }

  __syncthreads();
  float* red = xs;  // reuse as scratch: 4*64*20 = 5120 floats
#pragma unroll
  for (int d = 0; d < 20; ++d) red[wave * 1280 + lane * 20 + d] = acc[d];
  __syncthreads();
#pragma unroll
  for (int r = 0; r < 5; ++r) {
    int f = r * 256 + tid;  // 1280 outputs, f = t*20 + d
    float s = (red[f] + red[1280 + f]) + (red[2560 + f] + red[3840 + f]);
    O[f] = s + bv[f % 20];
  }
}

// TreeLSTM eval of one (pair, dim) unit, fully inline.
// Reads h_state rows A_/B2_, writes nh/nc[PS_*20+DD_], leaves h in HN_.
#define EVAL_UNIT(A_, B2_, PS_, DD_, HN_)                                     \
  {                                                                           \
    float ai = bc[DD_], af = bc[20 + DD_], ag = bc[40 + DD_],                 \
          au = bc[60 + DD_], ao = bc[80 + DD_];                               \
    const int xa_ = (A_)*20, xb_ = (B2_)*20, wr_ = (DD_)*44;                  \
    _Pragma("unroll")                                                         \
    for (int kq = 0; kq < 10; ++kq) {                                         \
      const float4 xq = (kq < 5)                                              \
          ? *(const float4*)(h_state + xa_ + kq * 4)                          \
          : *(const float4*)(h_state + xb_ + (kq - 5) * 4);                   \
      const float4 wi = *(const float4*)(Wt + wr_ + kq * 4);                  \
      const float4 wf = *(const float4*)(Wt + 880  + wr_ + kq * 4);           \
      const float4 wg = *(const float4*)(Wt + 1760 + wr_ + kq * 4);           \
      const float4 wu = *(const float4*)(Wt + 2640 + wr_ + kq * 4);           \
      const float4 wo = *(const float4*)(Wt + 3520 + wr_ + kq * 4);           \
      ai = fmaf(xq.x, wi.x, ai); ai = fmaf(xq.y, wi.y, ai);                   \
      ai = fmaf(xq.z, wi.z, ai); ai = fmaf(xq.w, wi.w, ai);                   \
      af = fmaf(xq.x, wf.x, af); af = fmaf(xq.y, wf.y, af);                   \
      af = fmaf(xq.z, wf.z, af); af = fmaf(xq.w, wf.w, af);                   \
      ag = fmaf(xq.x, wg.x, ag); ag = fmaf(xq.y, wg.y, ag);                   \
      ag = fmaf(xq.z, wg.z, ag); ag = fmaf(xq.w, wg.w, ag);                   \
      au = fmaf(xq.x, wu.x, au); au = fmaf(xq.y, wu.y, au);                   \
      au = fmaf(xq.z, wu.z, au); au = fmaf(xq.w, wu.w, au);                   \
      ao = fmaf(xq.x, wo.x, ao); ao = fmaf(xq.y, wo.y, ao);                   \
      ao = fmaf(xq.z, wo.z, ao); ao = fmaf(xq.w, wo.w, ao);                   \
    }                                                                         \
    const float cl_ = c_state[(A_)*20 + (DD_)],                               \
                cr_ = c_state[(B2_)*20 + (DD_)];                              \
    const float cn_ = cl_ * sigf(af + 1.0f) + cr_ * sigf(ag + 1.0f) +         \
                      tanhf(au) * sigf(ai);                                   \
    (HN_) = sigf(ao) * tanhf(cn_);                                            \
    nh[(PS_)*20 + (DD_)] = (HN_);                                             \
    nc[(PS_)*20 + (DD_)] = cn_;                                               \
  }

// ---------------------------------------------------------------------------
// Phase 2: per-row Gumbel tree pyramid, ONE WAVE per row.
// 64 threads/block, no __syncthreads anywhere, no register arrays.
// LDS ~39.2 KB -> 4 blocks/CU -> all 1024 rows resident.
// ---------------------------------------------------------------------------
__global__ __launch_bounds__(64, 1)
void pyramid_kernel(const float* __restrict__ H0, const float* __restrict__ C0,
                    const float* __restrict__ Wc, const float* __restrict__ bcg,
                    const float* __restrict__ query, const float* __restrict__ U,
                    const int* __restrict__ length, float* __restrict__ out) {
  __shared__ float h_state[64 * 20];
  __shared__ float c_state[64 * 20];
  __shared__ float nh[63 * 20];     // cached pair h_new, indexed by pair SLOT
  __shared__ float nc[63 * 20];     // cached pair c_new
  __shared__ float Wt[100 * 44];    // transposed W_comp: Wt[c][k], pitch 44
  __shared__ float bc[100];
  __shared__ float qv[20];
  __shared__ float lgt[64];         // logits, POSITION-indexed (shifted)
  __shared__ int   idxs[64];        // logical position -> h/c slot
  __shared__ int   pidx[64];        // logical pair -> nh/nc slot

  const int b    = blockIdx.x;
  const int lane = threadIdx.x;     // one wave: lane == tid
  int len = length[b];
  len = len < 1 ? 1 : (len > 64 ? 64 : len);

  // ---- stage (single wave; in-order DS pipeline orders everything) ----
  {
    const float4* h4 = (const float4*)(H0 + (size_t)b * kRowElems);
    const float4* c4 = (const float4*)(C0 + (size_t)b * kRowElems);
#pragma unroll
    for (int r = 0; r < 5; ++r) {
      int f = r * 64 + lane;  // 320 float4 per array
      ((float4*)h_state)[f] = h4[f];
      ((float4*)c_state)[f] = c4[f];
    }
  }
  for (int f = lane; f < 4000; f += 64) {
    int c = f / 40, k = f - c * 40;
    Wt[c * 44 + k] = Wc[k * 100 + c];
  }
  for (int f = lane; f < 100; f += 64) bc[f] = bcg[f];
  if (lane < 20) qv[lane] = query[lane];
  idxs[lane] = lane;
  pidx[lane] = lane;

  const int col = lane < 62 ? lane : 62;  // U row has 63 entries
  float u_next = U[b * kLM1 + col];       // row 0, consumed at i=0

  // ---- init: evaluate all 63 adjacent pairs (keep code small: unroll 1) ----
#pragma unroll 1
  for (int r = 0; r < 20; ++r) {
    int uu = r * 64 + lane;
    if (uu < 1260) {
      int p = uu / 20, dd = uu - p * 20;
      float hn_;
      EVAL_UNIT(p, p + 1, p, dd, hn_);
      (void)hn_;
    }
  }
  if (lane < 63) {
    float s = 0.0f;
#pragma unroll
    for (int d = 0; d < 20; ++d) s = fmaf(nh[lane * 20 + d], qv[d], s);
    lgt[lane] = s;
  }

  const int nIter = len - 1;
#pragma unroll 1
  for (int i = 0; i < nIter; ++i) {
    const int n = kL - i;  // current sequence length

    // ---- z = logit + gumbel; argmax (ties -> lowest index) ----
    const float g = -logf(-logf(u_next + 1e-20f) + 1e-20f);
    float zz = -FLT_MAX;
    int   ji = lane;
    if ((lane <= n - 2) && ((i + 1 + lane) < len)) zz = lgt[lane] + g;
#pragma unroll
    for (int off = 32; off > 0; off >>= 1) {
      float oz = __shfl_xor(zz, off);
      int   oi = __shfl_xor(ji, off);
      if (oz > zz || (oz == zz && oi < ji)) { zz = oz; ji = oi; }
    }
    const int k = ji;  // wave-uniform

    // ---- prefetch next gumbel row (single outstanding vmem) ----
    if (i + 1 < kLM1) u_next = U[(i + 1) * (kB * kLM1) + b * kLM1 + col];

    // ---- pre-shift reads: everything eval will need ----
    const int tgt = idxs[k];
    const int psk = pidx[k];
    int iA = 0, pA = 0, iB = 0;
    if (k >= 1)     { iA = idxs[k - 1]; pA = pidx[k - 1]; }
    if (k <= n - 3) { iB = idxs[k + 2]; }

    // ---- merge value + shift-source reads ----
    float nhv = 0.0f, ncv = 0.0f;
    if (lane < 20) { nhv = nh[psk * 20 + lane]; ncv = nc[psk * 20 + lane]; }
    const bool doI = (lane >= k + 1) && (lane <= n - 2);
    const bool doP = (lane >= k + 1) && (lane <= n - 3);
    const int  ln1 = lane < 63 ? lane + 1 : 63;
    int   vI = doI ? idxs[ln1] : 0;
    int   vP = doP ? pidx[ln1] : 0;
    float vL = doP ? lgt[ln1]  : 0.0f;
    __builtin_amdgcn_wave_barrier();  // reads above scheduled before writes below
    if (lane < 20) {
      h_state[tgt * 20 + lane] = nhv;
      c_state[tgt * 20 + lane] = ncv;
    }
    if (doI) idxs[lane] = vI;
    if (doP) { pidx[lane] = vP; lgt[lane] = vL; }

    // ---- evaluate the (<=2) invalidated pairs with PRE-shift indices ----
    if (i < len - 2) {
      const int p = lane >> 5, dd = lane & 31;
      int A = 0, B2 = 0, PS = 0, newpos = 0;
      bool act = false;
      if (p == 0) {
        if (k >= 1)          { A = iA;  B2 = tgt; PS = pA;  newpos = k - 1; act = (dd < 20); }
        else if (k <= n - 3) { A = tgt; B2 = iB;  PS = psk; newpos = k;     act = (dd < 20); }
      } else {
        if (k >= 1 && k <= n - 3) { A = tgt; B2 = iB; PS = psk; newpos = k; act = (dd < 20); }
      }
      float part = 0.0f;
      if (act) {
        float hn_;
        EVAL_UNIT(A, B2, PS, dd, hn_);
        part = hn_ * qv[dd];
      }
#pragma unroll
      for (int off = 16; off > 0; off >>= 1) part += __shfl_xor(part, off);
      if (act && dd == 0) lgt[newpos] = part;
    }
  }

  if (lane < 20) {
    out[b * 20 + lane] = h_state[idxs[0] * 20 + lane];
  }
}

}  // namespace

extern "C" void kernel_launch(void* const* d_in, const int* in_sizes, int n_in,
                              void* d_out, int out_size, void* d_ws, size_t ws_size,
                              hipStream_t stream) {
  const float* input_h  = (const float*)d_in[0];
  const float* input_c  = (const float*)d_in[1];
  const float* W_reduce = (const float*)d_in[2];
  const float* b_reduce = (const float*)d_in[3];
  const float* W_comp   = (const float*)d_in[4];
  const float* b_comp   = (const float*)d_in[5];
  const float* query    = (const float*)d_in[6];
  const float* u_noise  = (const float*)d_in[7];
  const int*   length   = (const int*)d_in[8];
  float* out = (float*)d_out;

  float* H0 = (float*)d_ws;
  float* C0 = H0 + (size_t)kB * kL * kLow;

  reduce_kernel<<<dim3(2 * kB), dim3(256), 0, stream>>>(
      input_h, input_c, W_reduce, b_reduce, H0, C0);
  pyramid_kernel<<<dim3(kB), dim3(64), 0, stream>>>(
      H0, C0, W_comp, b_comp, query, u_noise, length, out);
}